// Round 4
// baseline (92.019 us; speedup 1.0000x reference)
//
#include <hip/hip_runtime.h>
#include <hip/hip_bf16.h>

// Problem constants
#define NB    65536      // batch rows
#define ND    1024       // feature dim (K)
#define NT    64         // trees (N)
#define BK    128        // K-chunk in floats
#define NCH   (ND / BK)  // 8 chunks
#define WROWS 16         // rows per wave
#define ROWS  64         // rows per block (4 waves)

typedef __attribute__((ext_vector_type(8))) short bf16x8;
typedef __attribute__((ext_vector_type(4))) short bf16x4;
typedef __attribute__((ext_vector_type(4))) float f32x4;

__device__ __forceinline__ short f2bf_s(float f) {
    __hip_bfloat16 h = __float2bfloat16(f);
    return __builtin_bit_cast(short, h);
}

// ---- prep: feature_selectors [64][1024] f32 -> bf16 in d_ws ----
__global__ __launch_bounds__(256) void prep_kernel(const float* __restrict__ F,
                                                   __hip_bfloat16* __restrict__ Fb) {
    int idx = blockIdx.x * 256 + threadIdx.x;  // 256 blocks -> 65536 elements
    Fb[idx] = __float2bfloat16(F[idx]);
}

// ---- main: 4 fully independent waves per block; wave owns 16 rows x 64 trees.
// NO __syncthreads anywhere: per-wave private LDS double-buffer, waitcnt-paced.
template <bool PREPPED>
__global__ __launch_bounds__(256, 4) void node_main(const float* __restrict__ x,
                                                    const void* __restrict__ Fv,
                                                    const float* __restrict__ thr,
                                                    const float* __restrict__ lw,
                                                    float* __restrict__ out) {
    __shared__ __align__(16) __hip_bfloat16 Abuf[4][2][WROWS * BK];  // 4 waves x 2 x 4 KB

    const int tid  = threadIdx.x;
    const int w    = tid >> 6;       // wave id
    const int lane = tid & 63;
    const int c    = lane & 15;      // MFMA 16-index: A batch-row / B tree-col
    const int g    = lane >> 4;      // k-group
    const long waveRow = (long)blockIdx.x * ROWS + (long)w * WROWS;
    const float* xbase = x + waveRow * ND;

    // staging mapping: instr i covers rows {i*2, i*2+1}; 32 lanes x 16B contiguous per row
    const int srow2 = lane >> 5;     // 0..1
    const int scol  = lane & 31;     // float4 index within 512B row-chunk

    // per-lane tree constants: this lane's trees are {c, c+16, c+32, c+48}
    float thr_t[4], d0[4], d1[4], s0 = 0.f, s1 = 0.f;
#pragma unroll
    for (int nt = 0; nt < 4; ++nt) {
        const int t = nt * 16 + c;
        thr_t[nt] = thr[t];
        const float w00 = lw[t * 4 + 0], w01 = lw[t * 4 + 1];
        const float w10 = lw[t * 4 + 2], w11 = lw[t * 4 + 3];
        d0[nt] = w00 - w10;  d1[nt] = w01 - w11;
        s0 += w10;           s1 += w11;
    }

    const __hip_bfloat16* Fb = (const __hip_bfloat16*)Fv;
    const float*          Ff = (const float*)Fv;

    f32x4 acc[4];
#pragma unroll
    for (int nt = 0; nt < 4; ++nt) acc[nt] = (f32x4){0.f, 0.f, 0.f, 0.f};

    f32x4 rA[8];

    auto load_chunk = [&](int ch) {
#pragma unroll
        for (int i = 0; i < 8; ++i) {
            const int r = i * 2 + srow2;
            const f32x4* p = (const f32x4*)(xbase + (long)r * ND + ch * BK + scol * 4);
            rA[i] = __builtin_nontemporal_load(p);   // streamed, no reuse
        }
    };
    auto stage_write = [&](int buf) {
#pragma unroll
        for (int i = 0; i < 8; ++i) {
            const int r = i * 2 + srow2;
            f32x4 a = rA[i];
            bf16x4 v;
            v[0] = f2bf_s(a[0]); v[1] = f2bf_s(a[1]);
            v[2] = f2bf_s(a[2]); v[3] = f2bf_s(a[3]);
            const int s = (scol >> 1) ^ (r & 7);     // T2 XOR swizzle, 16B slots
            char* p = (char*)(&Abuf[w][buf][0]) + r * 256 + (s << 4) + ((scol & 1) << 3);
            *(bf16x4*)p = v;
        }
    };

    // prologue (no barrier: LDS is wave-private, waitcnt orders it)
    load_chunk(0);
    stage_write(0);
    load_chunk(1);

    for (int ch = 0; ch < NCH; ++ch) {
        const int cur = ch & 1;
        // stage next chunk, issue chunk+2 loads (overlap with this chunk's MFMA)
        if (ch < NCH - 1) {
            stage_write(cur ^ 1);
            if (ch < NCH - 2) load_chunk(ch + 2);
        }
        // compute chunk ch
#pragma unroll
        for (int kk = 0; kk < 4; ++kk) {
            const int slot = (kk * 4 + g) ^ (c & 7);
            bf16x8 afrag = *(const bf16x8*)(&Abuf[w][cur][c * BK + slot * 8]);
#pragma unroll
            for (int nt = 0; nt < 4; ++nt) {
                const long boff = (long)(nt * 16 + c) * ND + (long)ch * BK + kk * 32 + g * 8;
                bf16x8 bfrag;
                if constexpr (PREPPED) {
                    bfrag = *(const bf16x8*)(Fb + boff);
                } else {
                    f32x4 b0 = *(const f32x4*)(Ff + boff);
                    f32x4 b1 = *(const f32x4*)(Ff + boff + 4);
                    bfrag[0] = f2bf_s(b0[0]); bfrag[1] = f2bf_s(b0[1]);
                    bfrag[2] = f2bf_s(b0[2]); bfrag[3] = f2bf_s(b0[3]);
                    bfrag[4] = f2bf_s(b1[0]); bfrag[5] = f2bf_s(b1[1]);
                    bfrag[6] = f2bf_s(b1[2]); bfrag[7] = f2bf_s(b1[3]);
                }
                acc[nt] = __builtin_amdgcn_mfma_f32_16x16x32_bf16(afrag, bfrag, acc[nt], 0, 0, 0);
            }
        }
    }

    // ---- epilogue (wave-local): sigmoid + leaf combine + 16-lane tree reduce ----
    // D layout: col = c (tree-within-tile), row = g*4 + reg (batch row within 16)
#pragma unroll
    for (int reg = 0; reg < 4; ++reg) {
        float o0 = s0, o1 = s1;
#pragma unroll
        for (int nt = 0; nt < 4; ++nt) {
            const float logit = acc[nt][reg] - thr_t[nt];
            const float p = 1.0f / (1.0f + __expf(-logit));
            o0 += p * d0[nt];
            o1 += p * d1[nt];
        }
#pragma unroll
        for (int m = 1; m < 16; m <<= 1) {   // butterfly over the 16 c-lanes
            o0 += __shfl_xor(o0, m, 64);
            o1 += __shfl_xor(o1, m, 64);
        }
        if (c == 0) {
            const long row = waveRow + g * 4 + reg;
            *(float2*)(out + row * 2) = make_float2(o0, o1);
        }
    }
}

extern "C" void kernel_launch(void* const* d_in, const int* in_sizes, int n_in,
                              void* d_out, int out_size, void* d_ws, size_t ws_size,
                              hipStream_t stream) {
    const float* x   = (const float*)d_in[0];
    const float* fs  = (const float*)d_in[1];
    const float* thr = (const float*)d_in[2];
    const float* lw  = (const float*)d_in[3];
    float* out = (float*)d_out;
    (void)in_sizes; (void)n_in; (void)out_size;

    const size_t FB_BYTES = (size_t)NT * ND * sizeof(__hip_bfloat16);  // 128 KB
    if (ws_size >= FB_BYTES) {
        __hip_bfloat16* Fb = (__hip_bfloat16*)d_ws;
        prep_kernel<<<256, 256, 0, stream>>>(fs, Fb);
        node_main<true><<<NB / ROWS, 256, 0, stream>>>(x, (const void*)Fb, thr, lw, out);
    } else {
        node_main<false><<<NB / ROWS, 256, 0, stream>>>(x, (const void*)fs, thr, lw, out);
    }
}

// Round 5
// 54.921 us; speedup vs baseline: 1.6755x; 1.6755x over previous
//
#include <hip/hip_runtime.h>
#include <hip/hip_bf16.h>

// Problem constants
#define NB    65536      // batch rows
#define ND    1024       // feature dim (K)
#define NT    64         // trees (N)
#define BK    64         // K-chunk in floats
#define NCH   (ND / BK)  // 16 chunks
#define ROWS  64         // rows per block (4 waves; wave w owns trees [16w,16w+16))

typedef __attribute__((ext_vector_type(8))) short bf16x8;
typedef __attribute__((ext_vector_type(4))) short bf16x4;
typedef __attribute__((ext_vector_type(4))) float f32x4;

__device__ __forceinline__ short f2bf_s(float f) {
    __hip_bfloat16 h = __float2bfloat16(f);
    return __builtin_bit_cast(short, h);
}

// 256 threads / 4 waves. Double-buffered LDS (bf16, XOR-swizzled) + double-buffered
// staging registers: loads for chunk n+2 issue BEFORE compute(n), so they have
// ~2 compute phases to cover HBM latency. Compute BEFORE stage (R4 lesson).
__global__ __launch_bounds__(256, 4) void node_main(const float* __restrict__ x,
                                                    const float* __restrict__ F,
                                                    const float* __restrict__ thr,
                                                    const float* __restrict__ lw,
                                                    float* __restrict__ out) {
    __shared__ __align__(16) __hip_bfloat16 Abuf[2][ROWS * BK];   // 2 x 8 KB

    const int tid  = threadIdx.x;
    const int w    = tid >> 6;
    const int lane = tid & 63;
    const int c    = lane & 15;     // MFMA 16-index: batch row (A) / tree col (B)
    const int g    = lane >> 4;     // k-group
    const long blockRow = (long)blockIdx.x * ROWS;
    const float* xbase = x + blockRow * ND;

    // staging: pass i covers rows i*16 + srow; 16 lanes x 16B = 256B contiguous per row
    const int srow = tid >> 4;      // 0..15
    const int scol = tid & 15;      // f32x4 granule within row-chunk

    // per-lane tree constants (one tree per lane within the wave's 16-tree tile)
    const int   t     = w * 16 + c;
    const float thr_t = thr[t];
    const float w00 = lw[t * 4 + 0], w01 = lw[t * 4 + 1];
    const float w10 = lw[t * 4 + 2], w11 = lw[t * 4 + 3];
    const float* Frow = F + (long)t * ND;   // f32, L2-resident; cvt inline

    f32x4 acc[4];
#pragma unroll
    for (int rt = 0; rt < 4; ++rt) acc[rt] = (f32x4){0.f, 0.f, 0.f, 0.f};

    f32x4 rA0[4], rA1[4];   // two in-flight chunk buffers

    auto load_chunk = [&](int ch, f32x4* rA) {
#pragma unroll
        for (int i = 0; i < 4; ++i) {
            const int r = i * 16 + srow;
            rA[i] = *(const f32x4*)(xbase + (long)r * ND + ch * BK + scol * 4);
        }
    };
    auto stage_write = [&](int buf, const f32x4* rA) {
#pragma unroll
        for (int i = 0; i < 4; ++i) {
            const int r = i * 16 + srow;
            f32x4 a = rA[i];
            bf16x4 v;
            v[0] = f2bf_s(a[0]); v[1] = f2bf_s(a[1]);
            v[2] = f2bf_s(a[2]); v[3] = f2bf_s(a[3]);
            const int s = (scol >> 1) ^ (r & 7);      // T2 XOR swizzle, 16B slots
            char* p = (char*)(&Abuf[buf][0]) + r * 128 + (s << 4) + ((scol & 1) << 3);
            *(bf16x4*)p = v;
        }
    };
    auto compute = [&](int ch, int buf) {
#pragma unroll
        for (int kk = 0; kk < 2; ++kk) {
            // B fragment: inline f32->bf16 (L2-resident)
            const float* fp = Frow + ch * BK + kk * 32 + g * 8;
            f32x4 b0 = *(const f32x4*)(fp);
            f32x4 b1 = *(const f32x4*)(fp + 4);
            bf16x8 bfrag;
            bfrag[0] = f2bf_s(b0[0]); bfrag[1] = f2bf_s(b0[1]);
            bfrag[2] = f2bf_s(b0[2]); bfrag[3] = f2bf_s(b0[3]);
            bfrag[4] = f2bf_s(b1[0]); bfrag[5] = f2bf_s(b1[1]);
            bfrag[6] = f2bf_s(b1[2]); bfrag[7] = f2bf_s(b1[3]);
#pragma unroll
            for (int rt = 0; rt < 4; ++rt) {
                const int r    = rt * 16 + c;
                const int slot = (kk * 4 + g) ^ (r & 7);
                bf16x8 afrag = *(const bf16x8*)(&Abuf[buf][r * BK + slot * 8]);
                acc[rt] = __builtin_amdgcn_mfma_f32_16x16x32_bf16(afrag, bfrag, acc[rt], 0, 0, 0);
            }
        }
    };

    // prologue: chunks 0,1 in flight; stage 0
    load_chunk(0, rA0);
    load_chunk(1, rA1);
    stage_write(0, rA0);
    __syncthreads();

#pragma unroll
    for (int ch2 = 0; ch2 < NCH; ch2 += 2) {
        // ---- even phase: buf0 holds ch2 ----
        if (ch2 + 2 < NCH) load_chunk(ch2 + 2, rA0);   // issue early (rA0 already staged)
        compute(ch2, 0);
        stage_write(1, rA1);                           // chunk ch2+1 (loaded 1 iter ago)
        __syncthreads();
        // ---- odd phase: buf1 holds ch2+1 ----
        if (ch2 + 3 < NCH) load_chunk(ch2 + 3, rA1);
        compute(ch2 + 1, 1);
        if (ch2 + 2 < NCH) stage_write(0, rA0);
        __syncthreads();
    }

    // ---- epilogue: sigmoid + leaf combine + tree reduction ----
    float* partials = (float*)(&Abuf[0][0]);   // [4 waves][64 rows][2], aliased (safe post-barrier)
#pragma unroll
    for (int rt = 0; rt < 4; ++rt) {
#pragma unroll
        for (int reg = 0; reg < 4; ++reg) {
            const float logit = acc[rt][reg] - thr_t;
            const float p = 1.0f / (1.0f + __expf(-logit));
            float o0 = w10 + p * (w00 - w10);
            float o1 = w11 + p * (w01 - w11);
#pragma unroll
            for (int m = 1; m < 16; m <<= 1) {   // butterfly over 16 trees (c bits)
                o0 += __shfl_xor(o0, m, 64);
                o1 += __shfl_xor(o1, m, 64);
            }
            if (c == 0) {
                const int row = rt * 16 + g * 4 + reg;
                partials[(w * ROWS + row) * 2 + 0] = o0;
                partials[(w * ROWS + row) * 2 + 1] = o1;
            }
        }
    }
    __syncthreads();
    if (tid < 128) {
        const int row = tid >> 1, o = tid & 1;
        const float s = partials[(0 * ROWS + row) * 2 + o] + partials[(1 * ROWS + row) * 2 + o] +
                        partials[(2 * ROWS + row) * 2 + o] + partials[(3 * ROWS + row) * 2 + o];
        out[(blockRow + row) * 2 + o] = s;
    }
}

extern "C" void kernel_launch(void* const* d_in, const int* in_sizes, int n_in,
                              void* d_out, int out_size, void* d_ws, size_t ws_size,
                              hipStream_t stream) {
    const float* x   = (const float*)d_in[0];
    const float* fs  = (const float*)d_in[1];
    const float* thr = (const float*)d_in[2];
    const float* lw  = (const float*)d_in[3];
    float* out = (float*)d_out;
    (void)in_sizes; (void)n_in; (void)out_size; (void)d_ws; (void)ws_size;

    node_main<<<NB / ROWS, 256, 0, stream>>>(x, fs, thr, lw, out);
}

// Round 6
// 54.268 us; speedup vs baseline: 1.6956x; 1.0120x over previous
//
#include <hip/hip_runtime.h>
#include <hip/hip_bf16.h>

// Problem constants
#define NB    65536      // batch rows
#define ND    1024       // feature dim (K)
#define NT    64         // trees (N)
#define BK    64         // K-chunk in floats
#define NCH   (ND / BK)  // 16 chunks
#define ROWS  64         // rows per block (4 waves; wave w owns trees [16w,16w+16))

typedef __attribute__((ext_vector_type(8))) short bf16x8;
typedef __attribute__((ext_vector_type(4))) short bf16x4;
typedef __attribute__((ext_vector_type(4))) float f32x4;

__device__ __forceinline__ short f2bf_s(float f) {
    __hip_bfloat16 h = __float2bfloat16(f);
    return __builtin_bit_cast(short, h);
}

// Raw barrier WITHOUT the compiler's vmcnt(0) drain (T4): LDS ops must be complete
// (lgkmcnt in-order covers both our ds_writes and all ds_reads of the handed-over
// buffer), but global->REGISTER loads are private and may float across the barrier.
__device__ __forceinline__ void phase_barrier() {
    asm volatile("s_waitcnt lgkmcnt(0)\n\ts_barrier" ::: "memory");
}

// 256 threads / 4 waves. Double-buffered LDS (bf16, XOR-swizzled) + double-buffered
// staging registers; loads issue ~2 phases before their stage_write use and now
// stay in flight across barriers (counted vmcnt at use, not drain-0).
__global__ __launch_bounds__(256, 4) void node_main(const float* __restrict__ x,
                                                    const float* __restrict__ F,
                                                    const float* __restrict__ thr,
                                                    const float* __restrict__ lw,
                                                    float* __restrict__ out) {
    __shared__ __align__(16) __hip_bfloat16 Abuf[2][ROWS * BK];   // 2 x 8 KB

    const int tid  = threadIdx.x;
    const int w    = tid >> 6;
    const int lane = tid & 63;
    const int c    = lane & 15;     // MFMA 16-index: batch row (A) / tree col (B)
    const int g    = lane >> 4;     // k-group
    const long blockRow = (long)blockIdx.x * ROWS;
    const float* xbase = x + blockRow * ND;

    // staging: pass i covers rows i*16 + srow; 16 lanes x 16B = 256B contiguous per row
    const int srow = tid >> 4;      // 0..15
    const int scol = tid & 15;      // f32x4 granule within row-chunk

    // per-lane tree constants (one tree per lane within the wave's 16-tree tile)
    const int   t     = w * 16 + c;
    const float thr_t = thr[t];
    const float w00 = lw[t * 4 + 0], w01 = lw[t * 4 + 1];
    const float w10 = lw[t * 4 + 2], w11 = lw[t * 4 + 3];
    const float* Frow = F + (long)t * ND;   // f32, L2-resident; cvt inline

    f32x4 acc[4];
#pragma unroll
    for (int rt = 0; rt < 4; ++rt) acc[rt] = (f32x4){0.f, 0.f, 0.f, 0.f};

    f32x4 rA0[4], rA1[4];   // two in-flight chunk buffers

    auto load_chunk = [&](int ch, f32x4* rA) {
#pragma unroll
        for (int i = 0; i < 4; ++i) {
            const int r = i * 16 + srow;
            rA[i] = *(const f32x4*)(xbase + (long)r * ND + ch * BK + scol * 4);
        }
    };
    auto stage_write = [&](int buf, const f32x4* rA) {
#pragma unroll
        for (int i = 0; i < 4; ++i) {
            const int r = i * 16 + srow;
            f32x4 a = rA[i];
            bf16x4 v;
            v[0] = f2bf_s(a[0]); v[1] = f2bf_s(a[1]);
            v[2] = f2bf_s(a[2]); v[3] = f2bf_s(a[3]);
            const int s = (scol >> 1) ^ (r & 7);      // T2 XOR swizzle, 16B slots
            char* p = (char*)(&Abuf[buf][0]) + r * 128 + (s << 4) + ((scol & 1) << 3);
            *(bf16x4*)p = v;
        }
    };
    auto compute = [&](int ch, int buf) {
#pragma unroll
        for (int kk = 0; kk < 2; ++kk) {
            // B fragment: inline f32->bf16 (L2-resident)
            const float* fp = Frow + ch * BK + kk * 32 + g * 8;
            f32x4 b0 = *(const f32x4*)(fp);
            f32x4 b1 = *(const f32x4*)(fp + 4);
            bf16x8 bfrag;
            bfrag[0] = f2bf_s(b0[0]); bfrag[1] = f2bf_s(b0[1]);
            bfrag[2] = f2bf_s(b0[2]); bfrag[3] = f2bf_s(b0[3]);
            bfrag[4] = f2bf_s(b1[0]); bfrag[5] = f2bf_s(b1[1]);
            bfrag[6] = f2bf_s(b1[2]); bfrag[7] = f2bf_s(b1[3]);
#pragma unroll
            for (int rt = 0; rt < 4; ++rt) {
                const int r    = rt * 16 + c;
                const int slot = (kk * 4 + g) ^ (r & 7);
                bf16x8 afrag = *(const bf16x8*)(&Abuf[buf][r * BK + slot * 8]);
                acc[rt] = __builtin_amdgcn_mfma_f32_16x16x32_bf16(afrag, bfrag, acc[rt], 0, 0, 0);
            }
        }
    };

    // prologue: chunks 0,1 in flight; stage 0
    load_chunk(0, rA0);
    load_chunk(1, rA1);
    stage_write(0, rA0);
    phase_barrier();

#pragma unroll
    for (int ch2 = 0; ch2 < NCH; ch2 += 2) {
        // ---- even phase: buf0 holds ch2 ----
        if (ch2 + 2 < NCH) load_chunk(ch2 + 2, rA0);   // floats across barriers now
        compute(ch2, 0);
        stage_write(1, rA1);                           // rA1 loaded a full phase ago
        phase_barrier();
        // ---- odd phase: buf1 holds ch2+1 ----
        if (ch2 + 3 < NCH) load_chunk(ch2 + 3, rA1);
        compute(ch2 + 1, 1);
        if (ch2 + 2 < NCH) stage_write(0, rA0);
        phase_barrier();
    }

    // ---- epilogue: sigmoid + leaf combine + tree reduction ----
    float* partials = (float*)(&Abuf[0][0]);   // aliased; safe after last phase_barrier
#pragma unroll
    for (int rt = 0; rt < 4; ++rt) {
#pragma unroll
        for (int reg = 0; reg < 4; ++reg) {
            const float logit = acc[rt][reg] - thr_t;
            const float p = 1.0f / (1.0f + __expf(-logit));
            float o0 = w10 + p * (w00 - w10);
            float o1 = w11 + p * (w01 - w11);
#pragma unroll
            for (int m = 1; m < 16; m <<= 1) {   // butterfly over 16 trees (c bits)
                o0 += __shfl_xor(o0, m, 64);
                o1 += __shfl_xor(o1, m, 64);
            }
            if (c == 0) {
                const int row = rt * 16 + g * 4 + reg;
                partials[(w * ROWS + row) * 2 + 0] = o0;
                partials[(w * ROWS + row) * 2 + 1] = o1;
            }
        }
    }
    __syncthreads();
    if (tid < 128) {
        const int row = tid >> 1, o = tid & 1;
        const float s = partials[(0 * ROWS + row) * 2 + o] + partials[(1 * ROWS + row) * 2 + o] +
                        partials[(2 * ROWS + row) * 2 + o] + partials[(3 * ROWS + row) * 2 + o];
        out[(blockRow + row) * 2 + o] = s;
    }
}

extern "C" void kernel_launch(void* const* d_in, const int* in_sizes, int n_in,
                              void* d_out, int out_size, void* d_ws, size_t ws_size,
                              hipStream_t stream) {
    const float* x   = (const float*)d_in[0];
    const float* fs  = (const float*)d_in[1];
    const float* thr = (const float*)d_in[2];
    const float* lw  = (const float*)d_in[3];
    float* out = (float*)d_out;
    (void)in_sizes; (void)n_in; (void)out_size; (void)d_ws; (void)ws_size;

    node_main<<<NB / ROWS, 256, 0, stream>>>(x, fs, thr, lw, out);
}